// Round 1
// baseline (256.022 us; speedup 1.0000x reference)
//
#include <hip/hip_runtime.h>
#include <cstdint>
#include <cstddef>

#define HH 240
#define WW 320
#define HWPIX 76800
#define NVIEW 4
#define NCH 32
#define NGRP 8
#define NDEP 8
#define NNEI 9

// ws layout (in floats)
#define OFF_PROJ 0        // 4 views * 12 (rot 9 row-major, trans 3)
#define OFF_PW   48       // packed net: w0f[128] t0[16] w1f[128] t1[8] w2[8] b2[1] = 289
#define OFF_SN   340      // same packing (16B-aligned start)
#define OFF_Y    640      // NDEP*HWPIX = 614400
#define OFF_SRCT 615040   // NVIEW*HWPIX*NCH = 9830400

// -------- packed 8->16->8->1 MLP (BN pre-folded); returns pre-activation of last layer
__device__ __forceinline__ float mlp289(const float* __restrict__ p, const float x[8]) {
  float h0[16];
#pragma unroll
  for (int o = 0; o < 16; ++o) {
    float acc = p[128 + o];
#pragma unroll
    for (int i = 0; i < 8; ++i) acc = fmaf(p[o * 8 + i], x[i], acc);
    h0[o] = fmaxf(acc, 0.0f);
  }
  float h1[8];
#pragma unroll
  for (int o = 0; o < 8; ++o) {
    float acc = p[272 + o];
#pragma unroll
    for (int i = 0; i < 16; ++i) acc = fmaf(p[144 + o * 16 + i], h0[i], acc);
    h1[o] = fmaxf(acc, 0.0f);
  }
  float acc = p[288];
#pragma unroll
  for (int i = 0; i < 8; ++i) acc = fmaf(p[280 + i], h1[i], acc);
  return acc;
}

// -------- setup: proj matrices + BN folding
__global__ void k_setup(const float* __restrict__ refP, const float* __restrict__ srcP,
                        const float* __restrict__ pw0, const float* __restrict__ pbn0,
                        const float* __restrict__ pw1, const float* __restrict__ pbn1,
                        const float* __restrict__ pw2, const float* __restrict__ pb2,
                        const float* __restrict__ sw0, const float* __restrict__ sbn0,
                        const float* __restrict__ sw1, const float* __restrict__ sbn1,
                        const float* __restrict__ sw2, const float* __restrict__ sb2,
                        float* __restrict__ ws) {
  if (threadIdx.x != 0 || blockIdx.x != 0) return;
  // 4x4 inverse of refP via Gauss-Jordan with partial pivot
  float a[4][8];
  for (int i = 0; i < 4; ++i)
    for (int j = 0; j < 4; ++j) { a[i][j] = refP[i * 4 + j]; a[i][4 + j] = (i == j) ? 1.0f : 0.0f; }
  for (int c = 0; c < 4; ++c) {
    int piv = c; float best = fabsf(a[c][c]);
    for (int r = c + 1; r < 4; ++r) { float t = fabsf(a[r][c]); if (t > best) { best = t; piv = r; } }
    if (piv != c) for (int j = 0; j < 8; ++j) { float t = a[c][j]; a[c][j] = a[piv][j]; a[piv][j] = t; }
    float inv = 1.0f / a[c][c];
    for (int j = 0; j < 8; ++j) a[c][j] *= inv;
    for (int r = 0; r < 4; ++r) if (r != c) {
      float f = a[r][c];
      for (int j = 0; j < 8; ++j) a[r][j] -= f * a[c][j];
    }
  }
  for (int v = 0; v < NVIEW; ++v) {
    const float* S = srcP + v * 16;
    for (int i = 0; i < 3; ++i)
      for (int j = 0; j < 4; ++j) {
        float p = S[i*4+0]*a[0][4+j] + S[i*4+1]*a[1][4+j] + S[i*4+2]*a[2][4+j] + S[i*4+3]*a[3][4+j];
        if (j < 3) ws[v * 12 + i * 3 + j] = p;
        else       ws[v * 12 + 9 + i] = p;
      }
  }
  const float* W0[2] = {pw0, sw0}; const float* B0[2] = {pbn0, sbn0};
  const float* W1[2] = {pw1, sw1}; const float* B1[2] = {pbn1, sbn1};
  const float* W2[2] = {pw2, sw2}; const float* B2[2] = {pb2, sb2};
  const int offs[2] = {OFF_PW, OFF_SN};
  for (int k = 0; k < 2; ++k) {
    float* p = ws + offs[k];
    for (int o = 0; o < 16; ++o) {
      float g = B0[k][o], b = B0[k][16 + o], m = B0[k][32 + o], vv = B0[k][48 + o];
      float s = g / sqrtf(vv + 1e-5f);
      p[128 + o] = b - m * s;
      for (int i = 0; i < 8; ++i) p[o * 8 + i] = W0[k][o * 8 + i] * s;
    }
    for (int o = 0; o < 8; ++o) {
      float g = B1[k][o], b = B1[k][8 + o], m = B1[k][16 + o], vv = B1[k][24 + o];
      float s = g / sqrtf(vv + 1e-5f);
      p[272 + o] = b - m * s;
      for (int i = 0; i < 16; ++i) p[144 + o * 16 + i] = W1[k][o * 16 + i] * s;
    }
    for (int i = 0; i < 8; ++i) p[280 + i] = W2[k][i];
    p[288] = B2[k][0];
  }
}

// -------- transpose src_features (V,C,H,W) -> (V,H,W,C) for contiguous per-tap channel reads
__global__ __launch_bounds__(256) void k_transpose(const float* __restrict__ src,
                                                   float* __restrict__ dst) {
  int t = blockIdx.x * 256 + threadIdx.x;     // total NVIEW*HWPIX*8
  int c4 = t & 7;
  int vp = t >> 3;                            // v*HWPIX + pix
  int v = vp / HWPIX;
  int pix = vp - v * HWPIX;
  const float* s = src + ((size_t)(v * NCH + c4 * 4)) * HWPIX + pix;
  float4 val;
  val.x = s[0]; val.y = s[HWPIX]; val.z = s[2 * HWPIX]; val.w = s[3 * HWPIX];
  reinterpret_cast<float4*>(dst)[(size_t)vp * 8 + c4] = val;
}

__device__ __forceinline__ void tap_tr(float wt, const float* __restrict__ p,
                                       const float rc[NCH], float sim[NGRP]) {
  if (wt != 0.0f) {
    const float4* q = reinterpret_cast<const float4*>(p);
#pragma unroll
    for (int g = 0; g < NGRP; ++g) {
      float4 s4 = q[g];
      float dot = fmaf(s4.x, rc[4*g], fmaf(s4.y, rc[4*g+1], fmaf(s4.z, rc[4*g+2], s4.w * rc[4*g+3])));
      sim[g] = fmaf(wt, dot, sim[g]);
    }
  }
}

__device__ __forceinline__ void tap_dir(float wt, const float* __restrict__ p,
                                        const float rc[NCH], float sim[NGRP]) {
  if (wt != 0.0f) {
#pragma unroll
    for (int g = 0; g < NGRP; ++g) {
      float dot = 0.0f;
#pragma unroll
      for (int cc = 0; cc < 4; ++cc)
        dot = fmaf(p[(size_t)(g * 4 + cc) * HWPIX], rc[g * 4 + cc], dot);
      sim[g] = fmaf(wt, dot, sim[g]);
    }
  }
}

// -------- main fused kernel: warp+corr+pw-net+aggregate+similarity-net
// thread = (pix, d): lanes 0..7 of each 8-lane group share one pixel, span D.
__global__ __launch_bounds__(256) void k_main(
    const float* __restrict__ ref, const float* __restrict__ src,
    const float* __restrict__ depthS, const float* __restrict__ wsc,
    const float* __restrict__ srcT, float* __restrict__ ybuf,
    float* __restrict__ outVW, int useT) {
  int t = blockIdx.x * 256 + threadIdx.x;
  int d = t & 7;
  int pix = t >> 3;
  int h = pix / WW;
  int w = pix - h * WW;
  float fx = (float)w, fy = (float)h;

  float rc[NCH];
#pragma unroll
  for (int c = 0; c < NCH; ++c) rc[c] = ref[c * HWPIX + pix];
  float dep = depthS[d * HWPIX + pix];

  float ssum[NGRP];
#pragma unroll
  for (int g = 0; g < NGRP; ++g) ssum[g] = 0.0f;
  float wsum = 0.0f;

#pragma unroll 1
  for (int v = 0; v < NVIEW; ++v) {
    const float* pr = wsc + v * 12;
    float rx = fmaf(pr[0], fx, fmaf(pr[1], fy, pr[2]));
    float ry = fmaf(pr[3], fx, fmaf(pr[4], fy, pr[5]));
    float rz = fmaf(pr[6], fx, fmaf(pr[7], fy, pr[8]));
    float px_ = fmaf(rx, dep, pr[9]);
    float py_ = fmaf(ry, dep, pr[10]);
    float pz_ = fmaf(rz, dep, pr[11]);
    if (pz_ <= 0.001f) { px_ = (float)WW; py_ = (float)HH; pz_ = 1.0f; }
    float gx = px_ / pz_ * (2.0f / (float)(WW - 1)) - 1.0f;
    float gy = py_ / pz_ * (2.0f / (float)(HH - 1)) - 1.0f;
    float ix = (gx + 1.0f) * 0.5f * (float)(WW - 1);   // align_corners=True
    float iy = (gy + 1.0f) * 0.5f * (float)(HH - 1);
    float x0f = floorf(ix), y0f = floorf(iy);
    float wx1 = ix - x0f, wy1 = iy - y0f;
    float wx0 = 1.0f - wx1, wy0 = 1.0f - wy1;
    float x1f = x0f + 1.0f, y1f = y0f + 1.0f;
    bool vx0 = (x0f >= 0.0f) && (x0f <= (float)(WW - 1));
    bool vx1 = (x1f >= 0.0f) && (x1f <= (float)(WW - 1));
    bool vy0 = (y0f >= 0.0f) && (y0f <= (float)(HH - 1));
    bool vy1 = (y1f >= 0.0f) && (y1f <= (float)(HH - 1));
    int xa = (int)fminf(fmaxf(x0f, 0.0f), (float)(WW - 1));
    int xb = (int)fminf(fmaxf(x1f, 0.0f), (float)(WW - 1));
    int ya = (int)fminf(fmaxf(y0f, 0.0f), (float)(HH - 1));
    int yb = (int)fminf(fmaxf(y1f, 0.0f), (float)(HH - 1));
    float w00 = (vx0 && vy0) ? wx0 * wy0 : 0.0f;   // zeros_pad=True
    float w01 = (vx1 && vy0) ? wx1 * wy0 : 0.0f;
    float w10 = (vx0 && vy1) ? wx0 * wy1 : 0.0f;
    float w11 = (vx1 && vy1) ? wx1 * wy1 : 0.0f;

    float sim[NGRP];
#pragma unroll
    for (int g = 0; g < NGRP; ++g) sim[g] = 0.0f;

    if (useT) {
      const float* base = srcT + (size_t)v * HWPIX * NCH;
      tap_tr(w00, base + (size_t)(ya * WW + xa) * NCH, rc, sim);
      tap_tr(w01, base + (size_t)(ya * WW + xb) * NCH, rc, sim);
      tap_tr(w10, base + (size_t)(yb * WW + xa) * NCH, rc, sim);
      tap_tr(w11, base + (size_t)(yb * WW + xb) * NCH, rc, sim);
    } else {
      const float* base = src + (size_t)v * NCH * HWPIX;
      tap_dir(w00, base + ya * WW + xa, rc, sim);
      tap_dir(w01, base + ya * WW + xb, rc, sim);
      tap_dir(w10, base + yb * WW + xa, rc, sim);
      tap_dir(w11, base + yb * WW + xb, rc, sim);
    }
#pragma unroll
    for (int g = 0; g < NGRP; ++g) sim[g] *= 0.25f;  // mean over C/G=4

    float sc = mlp289(wsc + OFF_PW, sim);
    float vw = 1.0f / (1.0f + expf(-sc));            // sigmoid
    vw = fmaxf(vw, __shfl_xor(vw, 1, 8));            // max over D (8 lanes)
    vw = fmaxf(vw, __shfl_xor(vw, 2, 8));
    vw = fmaxf(vw, __shfl_xor(vw, 4, 8));
#pragma unroll
    for (int g = 0; g < NGRP; ++g) ssum[g] = fmaf(sim[g], vw, ssum[g]);
    wsum += vw;
    if (d == 0) outVW[v * HWPIX + pix] = vw;
  }

  float xg[NGRP];
#pragma unroll
  for (int g = 0; g < NGRP; ++g) xg[g] = ssum[g] / wsum;
  float yv = mlp289(wsc + OFF_SN, xg);
  ybuf[d * HWPIX + pix] = yv;
}

// -------- score: 9-neighbor grid_sample of y + weight dot + softmax + depth
__global__ __launch_bounds__(256) void k_score(
    const float* __restrict__ grid, const float* __restrict__ weight,
    const float* __restrict__ depthS, const float* __restrict__ ybuf,
    float* __restrict__ out) {
  int t = blockIdx.x * 256 + threadIdx.x;
  int d = t & 7;
  int pix = t >> 3;
  int h = pix / WW;
  int w = pix - h * WW;
  const float* yb = ybuf + d * HWPIX;
  float sv = 0.0f;
#pragma unroll 1
  for (int n = 0; n < NNEI; ++n) {
    int gi = ((n * HH + h) * WW + w) * 2;
    float gx = grid[gi], gy = grid[gi + 1];
    float ix = ((gx + 1.0f) * (float)WW - 1.0f) * 0.5f;  // align_corners=False
    float iy = ((gy + 1.0f) * (float)HH - 1.0f) * 0.5f;
    float x0f = floorf(ix), y0f = floorf(iy);
    float wx1 = ix - x0f, wy1 = iy - y0f;
    float wx0 = 1.0f - wx1, wy0 = 1.0f - wy1;
    int xa = (int)fminf(fmaxf(x0f, 0.0f), (float)(WW - 1));
    int xb = (int)fminf(fmaxf(x0f + 1.0f, 0.0f), (float)(WW - 1));
    int ya = (int)fminf(fmaxf(y0f, 0.0f), (float)(HH - 1));
    int yb2 = (int)fminf(fmaxf(y0f + 1.0f, 0.0f), (float)(HH - 1));
    float v00 = yb[ya * WW + xa], v01 = yb[ya * WW + xb];
    float v10 = yb[yb2 * WW + xa], v11 = yb[yb2 * WW + xb];
    float s = wy0 * fmaf(wx0, v00, wx1 * v01) + wy1 * fmaf(wx0, v10, wx1 * v11);
    float wn = weight[((d * NNEI + n) * HH + h) * WW + w];
    sv = fmaf(s, wn, sv);
  }
  // softmax over d (8 lanes) + depth regression
  float m = sv;
  m = fmaxf(m, __shfl_xor(m, 1, 8));
  m = fmaxf(m, __shfl_xor(m, 2, 8));
  m = fmaxf(m, __shfl_xor(m, 4, 8));
  float e = expf(sv - m);
  float s8 = e;
  s8 += __shfl_xor(s8, 1, 8);
  s8 += __shfl_xor(s8, 2, 8);
  s8 += __shfl_xor(s8, 4, 8);
  float sc = e / s8;
  out[HWPIX + d * HWPIX + pix] = sc;           // score
  float dp = depthS[d * HWPIX + pix] * sc;
  dp += __shfl_xor(dp, 1, 8);
  dp += __shfl_xor(dp, 2, 8);
  dp += __shfl_xor(dp, 4, 8);
  if (d == 0) out[pix] = dp;                   // depth
}

extern "C" void kernel_launch(void* const* d_in, const int* in_sizes, int n_in,
                              void* d_out, int out_size, void* d_ws, size_t ws_size,
                              hipStream_t stream) {
  const float* ref    = (const float*)d_in[0];
  const float* src    = (const float*)d_in[1];
  const float* refP   = (const float*)d_in[2];
  const float* srcP   = (const float*)d_in[3];
  const float* depthS = (const float*)d_in[4];
  const float* grid   = (const float*)d_in[5];
  const float* weight = (const float*)d_in[6];
  const float* pw0  = (const float*)d_in[7];
  const float* pbn0 = (const float*)d_in[8];
  const float* pw1  = (const float*)d_in[9];
  const float* pbn1 = (const float*)d_in[10];
  const float* pw2  = (const float*)d_in[11];
  const float* pb2  = (const float*)d_in[12];
  const float* sw0  = (const float*)d_in[13];
  const float* sbn0 = (const float*)d_in[14];
  const float* sw1  = (const float*)d_in[15];
  const float* sbn1 = (const float*)d_in[16];
  const float* sw2  = (const float*)d_in[17];
  const float* sb2  = (const float*)d_in[18];
  float* out = (float*)d_out;
  float* ws  = (float*)d_ws;

  size_t needFull = (size_t)(OFF_SRCT + (size_t)NVIEW * HWPIX * NCH) * sizeof(float);
  int useT = (ws_size >= needFull) ? 1 : 0;

  k_setup<<<1, 64, 0, stream>>>(refP, srcP, pw0, pbn0, pw1, pbn1, pw2, pb2,
                                sw0, sbn0, sw1, sbn1, sw2, sb2, ws);
  if (useT)
    k_transpose<<<(NVIEW * HWPIX * 8) / 256, 256, 0, stream>>>(src, ws + OFF_SRCT);
  k_main<<<(HWPIX * 8) / 256, 256, 0, stream>>>(ref, src, depthS, ws, ws + OFF_SRCT,
                                                ws + OFF_Y, out + 9 * HWPIX, useT);
  k_score<<<(HWPIX * 8) / 256, 256, 0, stream>>>(grid, weight, depthS, ws + OFF_Y, out);
}

// Round 2
// 174.439 us; speedup vs baseline: 1.4677x; 1.4677x over previous
//
#include <hip/hip_runtime.h>
#include <cstdint>
#include <cstddef>

#define HH 240
#define WW 320
#define HWPIX 76800
#define NVIEW 4
#define NCH 32
#define NGRP 8
#define NDEP 8
#define NNEI 9

// ws layout (in floats)
#define OFF_PROJ 0        // 4 views * 12 (rot 9 row-major, trans 3)
#define OFF_PW   48       // packed net: w0f[128] t0[16] w1f[128] t1[8] w2[8] b2[1] = 289
#define OFF_SN   340      // same packing
#define OFF_Y    640      // NDEP*HWPIX = 614400  (layout [pix][d])
#define OFF_SRCT 615040   // 5 planes * HWPIX * NCH (4 src views + ref)

// -------- packed 8->16->8->1 MLP (BN pre-folded); returns pre-activation of last layer
__device__ __forceinline__ float mlp289(const float* __restrict__ p, const float x[8]) {
  float h0[16];
#pragma unroll
  for (int o = 0; o < 16; ++o) {
    float acc = p[128 + o];
#pragma unroll
    for (int i = 0; i < 8; ++i) acc = fmaf(p[o * 8 + i], x[i], acc);
    h0[o] = fmaxf(acc, 0.0f);
  }
  float h1[8];
#pragma unroll
  for (int o = 0; o < 8; ++o) {
    float acc = p[272 + o];
#pragma unroll
    for (int i = 0; i < 16; ++i) acc = fmaf(p[144 + o * 16 + i], h0[i], acc);
    h1[o] = fmaxf(acc, 0.0f);
  }
  float acc = p[288];
#pragma unroll
  for (int i = 0; i < 8; ++i) acc = fmaf(p[280 + i], h1[i], acc);
  return acc;
}

// -------- setup: proj matrices (1 lane) + BN folding (lane-parallel)
__global__ void k_setup(const float* __restrict__ refP, const float* __restrict__ srcP,
                        const float* __restrict__ pw0, const float* __restrict__ pbn0,
                        const float* __restrict__ pw1, const float* __restrict__ pbn1,
                        const float* __restrict__ pw2, const float* __restrict__ pb2,
                        const float* __restrict__ sw0, const float* __restrict__ sbn0,
                        const float* __restrict__ sw1, const float* __restrict__ sbn1,
                        const float* __restrict__ sw2, const float* __restrict__ sb2,
                        float* __restrict__ ws) {
  int tid = threadIdx.x;
  if (tid == 578) {
    // 4x4 inverse of refP via Gauss-Jordan with partial pivot, then proj = srcP * inv
    float a[4][8];
    for (int i = 0; i < 4; ++i)
      for (int j = 0; j < 4; ++j) { a[i][j] = refP[i * 4 + j]; a[i][4 + j] = (i == j) ? 1.0f : 0.0f; }
    for (int c = 0; c < 4; ++c) {
      int piv = c; float best = fabsf(a[c][c]);
      for (int r = c + 1; r < 4; ++r) { float t = fabsf(a[r][c]); if (t > best) { best = t; piv = r; } }
      if (piv != c) for (int j = 0; j < 8; ++j) { float t = a[c][j]; a[c][j] = a[piv][j]; a[piv][j] = t; }
      float inv = 1.0f / a[c][c];
      for (int j = 0; j < 8; ++j) a[c][j] *= inv;
      for (int r = 0; r < 4; ++r) if (r != c) {
        float f = a[r][c];
        for (int j = 0; j < 8; ++j) a[r][j] -= f * a[c][j];
      }
    }
    for (int v = 0; v < NVIEW; ++v) {
      const float* S = srcP + v * 16;
      for (int i = 0; i < 3; ++i)
        for (int j = 0; j < 4; ++j) {
          float p = S[i*4+0]*a[0][4+j] + S[i*4+1]*a[1][4+j] + S[i*4+2]*a[2][4+j] + S[i*4+3]*a[3][4+j];
          if (j < 3) ws[v * 12 + i * 3 + j] = p;
          else       ws[v * 12 + 9 + i] = p;
        }
    }
    return;
  }
  if (tid >= 578) return;
  int k = tid / 289;          // which net: 0=pw, 1=sn
  int j = tid - k * 289;      // element within packed net
  const float* W0 = k ? sw0 : pw0;  const float* B0 = k ? sbn0 : pbn0;
  const float* W1 = k ? sw1 : pw1;  const float* B1 = k ? sbn1 : pbn1;
  const float* W2 = k ? sw2 : pw2;  const float* B2 = k ? sb2 : pb2;
  float* p = ws + (k ? OFF_SN : OFF_PW);
  if (j < 128) {                       // layer0 weights, folded BN scale * 0.25 group-mean
    int o = j >> 3;
    float s = B0[o] / sqrtf(B0[48 + o] + 1e-5f);
    p[j] = W0[j] * s * 0.25f;
  } else if (j < 144) {                // layer0 bias
    int o = j - 128;
    float s = B0[o] / sqrtf(B0[48 + o] + 1e-5f);
    p[j] = B0[16 + o] - B0[32 + o] * s;
  } else if (j < 272) {                // layer1 weights
    int idx = j - 144; int o = idx >> 4;
    float s = B1[o] / sqrtf(B1[24 + o] + 1e-5f);
    p[j] = W1[idx] * s;
  } else if (j < 280) {                // layer1 bias
    int o = j - 272;
    float s = B1[o] / sqrtf(B1[24 + o] + 1e-5f);
    p[j] = B1[8 + o] - B1[16 + o] * s;
  } else if (j < 288) {
    p[j] = W2[j - 280];
  } else {
    p[j] = B2[0];
  }
}

// -------- transpose (V,C,H,W) -> (V,H,W,C); plane 4 = ref_feature
__global__ __launch_bounds__(256) void k_transpose(const float* __restrict__ src,
                                                   const float* __restrict__ ref,
                                                   float* __restrict__ dst, int total) {
  int t = blockIdx.x * 256 + threadIdx.x;
  if (t >= total) return;
  int c4 = t & 7;
  int vp = t >> 3;
  int v = vp / HWPIX;
  int pix = vp - v * HWPIX;
  const float* s = (v < NVIEW) ? (src + ((size_t)(v * NCH + c4 * 4)) * HWPIX + pix)
                               : (ref + ((size_t)(c4 * 4)) * HWPIX + pix);
  float4 val;
  val.x = s[0]; val.y = s[HWPIX]; val.z = s[2 * HWPIX]; val.w = s[3 * HWPIX];
  reinterpret_cast<float4*>(dst)[(size_t)vp * 8 + c4] = val;
}

__device__ __forceinline__ void tap_tr(float wt, const float* __restrict__ p,
                                       const float rc[NCH], float sim[NGRP]) {
  const float4* q = reinterpret_cast<const float4*>(p);
#pragma unroll
  for (int g = 0; g < NGRP; ++g) {
    float4 s4 = q[g];
    float dot = fmaf(s4.x, rc[4*g], fmaf(s4.y, rc[4*g+1], fmaf(s4.z, rc[4*g+2], s4.w * rc[4*g+3])));
    sim[g] = fmaf(wt, dot, sim[g]);
  }
}

__device__ __forceinline__ void tap_dir(float wt, const float* __restrict__ p,
                                        const float rc[NCH], float sim[NGRP]) {
#pragma unroll
  for (int g = 0; g < NGRP; ++g) {
    float dot = 0.0f;
#pragma unroll
    for (int cc = 0; cc < 4; ++cc)
      dot = fmaf(p[(size_t)(g * 4 + cc) * HWPIX], rc[g * 4 + cc], dot);
    sim[g] = fmaf(wt, dot, sim[g]);
  }
}

// -------- main fused kernel: warp+corr+pw-net+aggregate+similarity-net
// thread = (pix, d): lanes 0..7 of each 8-lane cluster share one pixel, span D.
__global__ __launch_bounds__(256) void k_main(
    const float* __restrict__ ref, const float* __restrict__ src,
    const float* __restrict__ depthS, const float* __restrict__ wsc,
    const float* __restrict__ srcT, float* __restrict__ ybuf,
    float* __restrict__ outVW, int mode) {   // mode: 0 = no transpose, 1 = srcT, 2 = srcT+refT
  int t = blockIdx.x * 256 + threadIdx.x;
  int d = t & 7;
  int pix = t >> 3;
  int h = pix / WW;
  int w = pix - h * WW;
  float fx = (float)w, fy = (float)h;

  float rc[NCH];
  if (mode == 2) {
    const float4* rp = reinterpret_cast<const float4*>(srcT + (size_t)NVIEW * HWPIX * NCH + (size_t)pix * NCH);
#pragma unroll
    for (int g = 0; g < NGRP; ++g) {
      float4 q = rp[g];
      rc[4*g] = q.x; rc[4*g+1] = q.y; rc[4*g+2] = q.z; rc[4*g+3] = q.w;
    }
  } else {
#pragma unroll
    for (int c = 0; c < NCH; ++c) rc[c] = ref[c * HWPIX + pix];
  }
  float dep = depthS[d * HWPIX + pix];

  float ssum[NGRP];
#pragma unroll
  for (int g = 0; g < NGRP; ++g) ssum[g] = 0.0f;
  float wsum = 0.0f;

#pragma unroll 2
  for (int v = 0; v < NVIEW; ++v) {
    const float* pr = wsc + v * 12;
    float rx = fmaf(pr[0], fx, fmaf(pr[1], fy, pr[2]));
    float ry = fmaf(pr[3], fx, fmaf(pr[4], fy, pr[5]));
    float rz = fmaf(pr[6], fx, fmaf(pr[7], fy, pr[8]));
    float pz_ = fmaf(rz, dep, pr[11]);
    bool neg = (pz_ <= 0.001f);
    float px_ = neg ? (float)WW : fmaf(rx, dep, pr[9]);
    float py_ = neg ? (float)HH : fmaf(ry, dep, pr[10]);
    float rpz = neg ? 1.0f : __fdividef(1.0f, pz_);
    // align_corners=True: ix = ((px/pz)/((W-1)/2) - 1 + 1)*0.5*(W-1) = px/pz
    float ix = px_ * rpz;
    float iy = py_ * rpz;
    float x0f = floorf(ix), y0f = floorf(iy);
    float wx1 = ix - x0f, wy1 = iy - y0f;
    float wx0 = 1.0f - wx1, wy0 = 1.0f - wy1;
    float x1f = x0f + 1.0f, y1f = y0f + 1.0f;
    float vx0 = (x0f >= 0.0f && x0f <= (float)(WW - 1)) ? 1.0f : 0.0f;
    float vx1 = (x1f >= 0.0f && x1f <= (float)(WW - 1)) ? 1.0f : 0.0f;
    float vy0 = (y0f >= 0.0f && y0f <= (float)(HH - 1)) ? 1.0f : 0.0f;
    float vy1 = (y1f >= 0.0f && y1f <= (float)(HH - 1)) ? 1.0f : 0.0f;
    int xa = (int)fminf(fmaxf(x0f, 0.0f), (float)(WW - 1));
    int xb = (int)fminf(fmaxf(x1f, 0.0f), (float)(WW - 1));
    int ya = (int)fminf(fmaxf(y0f, 0.0f), (float)(HH - 1));
    int yb = (int)fminf(fmaxf(y1f, 0.0f), (float)(HH - 1));
    float w00 = wx0 * wy0 * vx0 * vy0;   // zeros_pad=True
    float w01 = wx1 * wy0 * vx1 * vy0;
    float w10 = wx0 * wy1 * vx0 * vy1;
    float w11 = wx1 * wy1 * vx1 * vy1;

    float sim[NGRP];
#pragma unroll
    for (int g = 0; g < NGRP; ++g) sim[g] = 0.0f;

    if (mode >= 1) {
      const float* base = srcT + (size_t)v * HWPIX * NCH;
      tap_tr(w00, base + (size_t)(ya * WW + xa) * NCH, rc, sim);
      tap_tr(w01, base + (size_t)(ya * WW + xb) * NCH, rc, sim);
      tap_tr(w10, base + (size_t)(yb * WW + xa) * NCH, rc, sim);
      tap_tr(w11, base + (size_t)(yb * WW + xb) * NCH, rc, sim);
    } else {
      const float* base = src + (size_t)v * NCH * HWPIX;
      tap_dir(w00, base + ya * WW + xa, rc, sim);
      tap_dir(w01, base + ya * WW + xb, rc, sim);
      tap_dir(w10, base + yb * WW + xa, rc, sim);
      tap_dir(w11, base + yb * WW + xb, rc, sim);
    }
    // group-mean 0.25 folded into both nets' layer0 weights at setup

    float sc = mlp289(wsc + OFF_PW, sim);
    float vw = __fdividef(1.0f, 1.0f + __expf(-sc));   // sigmoid, fast path
    vw = fmaxf(vw, __shfl_xor(vw, 1, 8));              // max over D (8 lanes)
    vw = fmaxf(vw, __shfl_xor(vw, 2, 8));
    vw = fmaxf(vw, __shfl_xor(vw, 4, 8));
#pragma unroll
    for (int g = 0; g < NGRP; ++g) ssum[g] = fmaf(sim[g], vw, ssum[g]);
    wsum += vw;
    if (d == 0) outVW[v * HWPIX + pix] = vw;
  }

  float rw = __fdividef(1.0f, wsum);
  float xg[NGRP];
#pragma unroll
  for (int g = 0; g < NGRP; ++g) xg[g] = ssum[g] * rw;
  float yv = mlp289(wsc + OFF_SN, xg);
  ybuf[pix * NDEP + d] = yv;             // [pix][d] layout — coalesced, d contiguous
}

// -------- score: 9-neighbor grid_sample of y + weight dot + softmax + depth
__global__ __launch_bounds__(256) void k_score(
    const float* __restrict__ grid, const float* __restrict__ weight,
    const float* __restrict__ depthS, const float* __restrict__ ybuf,
    float* __restrict__ out) {
  int t = blockIdx.x * 256 + threadIdx.x;
  int d = t & 7;
  int pix = t >> 3;
  int h = pix / WW;
  int w = pix - h * WW;
  float sv = 0.0f;
#pragma unroll 1
  for (int n = 0; n < NNEI; ++n) {
    int gi = ((n * HH + h) * WW + w) * 2;
    float gx = grid[gi], gy = grid[gi + 1];
    float ix = ((gx + 1.0f) * (float)WW - 1.0f) * 0.5f;  // align_corners=False
    float iy = ((gy + 1.0f) * (float)HH - 1.0f) * 0.5f;
    float x0f = floorf(ix), y0f = floorf(iy);
    float wx1 = ix - x0f, wy1 = iy - y0f;
    float wx0 = 1.0f - wx1, wy0 = 1.0f - wy1;
    int xa = (int)fminf(fmaxf(x0f, 0.0f), (float)(WW - 1));
    int xb = (int)fminf(fmaxf(x0f + 1.0f, 0.0f), (float)(WW - 1));
    int ya = (int)fminf(fmaxf(y0f, 0.0f), (float)(HH - 1));
    int yb2 = (int)fminf(fmaxf(y0f + 1.0f, 0.0f), (float)(HH - 1));
    // ybuf is [pix][d]: each 8-lane cluster reads one contiguous 32B segment per tap
    float v00 = ybuf[(ya * WW + xa) * NDEP + d], v01 = ybuf[(ya * WW + xb) * NDEP + d];
    float v10 = ybuf[(yb2 * WW + xa) * NDEP + d], v11 = ybuf[(yb2 * WW + xb) * NDEP + d];
    float s = wy0 * fmaf(wx0, v00, wx1 * v01) + wy1 * fmaf(wx0, v10, wx1 * v11);
    float wn = weight[((d * NNEI + n) * HH + h) * WW + w];
    sv = fmaf(s, wn, sv);
  }
  // softmax over d (8 lanes) + depth regression
  float m = sv;
  m = fmaxf(m, __shfl_xor(m, 1, 8));
  m = fmaxf(m, __shfl_xor(m, 2, 8));
  m = fmaxf(m, __shfl_xor(m, 4, 8));
  float e = __expf(sv - m);
  float s8 = e;
  s8 += __shfl_xor(s8, 1, 8);
  s8 += __shfl_xor(s8, 2, 8);
  s8 += __shfl_xor(s8, 4, 8);
  float sc = __fdividef(e, s8);
  out[HWPIX + d * HWPIX + pix] = sc;           // score
  float dp = depthS[d * HWPIX + pix] * sc;
  dp += __shfl_xor(dp, 1, 8);
  dp += __shfl_xor(dp, 2, 8);
  dp += __shfl_xor(dp, 4, 8);
  if (d == 0) out[pix] = dp;                   // depth
}

extern "C" void kernel_launch(void* const* d_in, const int* in_sizes, int n_in,
                              void* d_out, int out_size, void* d_ws, size_t ws_size,
                              hipStream_t stream) {
  const float* ref    = (const float*)d_in[0];
  const float* src    = (const float*)d_in[1];
  const float* refP   = (const float*)d_in[2];
  const float* srcP   = (const float*)d_in[3];
  const float* depthS = (const float*)d_in[4];
  const float* grid   = (const float*)d_in[5];
  const float* weight = (const float*)d_in[6];
  const float* pw0  = (const float*)d_in[7];
  const float* pbn0 = (const float*)d_in[8];
  const float* pw1  = (const float*)d_in[9];
  const float* pbn1 = (const float*)d_in[10];
  const float* pw2  = (const float*)d_in[11];
  const float* pb2  = (const float*)d_in[12];
  const float* sw0  = (const float*)d_in[13];
  const float* sbn0 = (const float*)d_in[14];
  const float* sw1  = (const float*)d_in[15];
  const float* sbn1 = (const float*)d_in[16];
  const float* sw2  = (const float*)d_in[17];
  const float* sb2  = (const float*)d_in[18];
  float* out = (float*)d_out;
  float* ws  = (float*)d_ws;

  size_t needSrc = (size_t)(OFF_SRCT + (size_t)NVIEW * HWPIX * NCH) * sizeof(float);
  size_t needAll = (size_t)(OFF_SRCT + (size_t)(NVIEW + 1) * HWPIX * NCH) * sizeof(float);
  int mode = (ws_size >= needAll) ? 2 : (ws_size >= needSrc ? 1 : 0);

  k_setup<<<1, 640, 0, stream>>>(refP, srcP, pw0, pbn0, pw1, pbn1, pw2, pb2,
                                 sw0, sbn0, sw1, sbn1, sw2, sb2, ws);
  if (mode >= 1) {
    int nplanes = (mode == 2) ? (NVIEW + 1) : NVIEW;
    int total = nplanes * HWPIX * 8;
    k_transpose<<<(total + 255) / 256, 256, 0, stream>>>(src, ref, ws + OFF_SRCT, total);
  }
  k_main<<<(HWPIX * 8) / 256, 256, 0, stream>>>(ref, src, depthS, ws, ws + OFF_SRCT,
                                                ws + OFF_Y, out + 9 * HWPIX, mode);
  k_score<<<(HWPIX * 8) / 256, 256, 0, stream>>>(grid, weight, depthS, ws + OFF_Y, out);
}

// Round 4
// 91.601 us; speedup vs baseline: 2.7950x; 1.9043x over previous
//
#include <hip/hip_runtime.h>
#include <hip/hip_fp16.h>
#include <cstdint>
#include <cstddef>

#define HH 240
#define WW 320
#define HWPIX 76800
#define NVIEW 4
#define NCH 32
#define NGRP 8
#define NDEP 8
#define NNEI 9
#define SPLANE (HWPIX * NCH)   // halfs per feature plane

// ws layout (in floats)
#define OFF_PROJ 0    // 4 views * 12 (rot 9 row-major, trans 3)
// packed net (157 floats each): [0..64) w0 as 128 f16 (row-major 16x8, BN*0.25 folded)
//                               [64..128) w1 as 128 f16 (8x16, BN folded)
//                               [128..132) w2 as 8 f16
//                               [132..148) b0 f32, [148..156) b1 f32, [156] b2 f32
#define OFF_PW   48
#define OFF_SN   208
#define OFF_Y    640      // NDEP*HWPIX f32, layout [pix][d]
#define OFF_SRCT 615040   // as __half*: 5 planes (4 src + ref) * HWPIX * NCH

typedef _Float16 h2 __attribute__((ext_vector_type(2)));

__device__ __forceinline__ float fdot2_(h2 a, h2 b, float c) {
#if __has_builtin(__builtin_amdgcn_fdot2)
  return __builtin_amdgcn_fdot2(a, b, c, false);
#else
  return c + (float)a.x * (float)b.x + (float)a.y * (float)b.y;
#endif
}
__device__ __forceinline__ h2 pk_(float a, float b) {
#if __has_builtin(__builtin_amdgcn_cvt_pkrtz)
  return __builtin_bit_cast(h2, __builtin_amdgcn_cvt_pkrtz(a, b));
#else
  h2 r; r.x = (_Float16)a; r.y = (_Float16)b; return r;
#endif
}

// -------- packed f16 MLP 8->16->8->1 (BN pre-folded); returns last pre-activation
__device__ __forceinline__ float mlp_h(const float* __restrict__ p, const h2 x[4]) {
  const h2* w0 = (const h2*)p;          // 64 h2
  const h2* w1 = (const h2*)(p + 64);   // 64 h2
  const h2* w2 = (const h2*)(p + 128);  // 4 h2
  h2 hx[8];
#pragma unroll
  for (int o = 0; o < 8; ++o) {
    float a0 = p[132 + 2 * o], a1 = p[132 + 2 * o + 1];
#pragma unroll
    for (int i = 0; i < 4; ++i) {
      a0 = fdot2_(w0[(2 * o) * 4 + i], x[i], a0);
      a1 = fdot2_(w0[(2 * o + 1) * 4 + i], x[i], a1);
    }
    hx[o] = pk_(fmaxf(a0, 0.0f), fmaxf(a1, 0.0f));
  }
  h2 hy[4];
#pragma unroll
  for (int o = 0; o < 4; ++o) {
    float a0 = p[148 + 2 * o], a1 = p[148 + 2 * o + 1];
#pragma unroll
    for (int i = 0; i < 8; ++i) {
      a0 = fdot2_(w1[(2 * o) * 8 + i], hx[i], a0);
      a1 = fdot2_(w1[(2 * o + 1) * 8 + i], hx[i], a1);
    }
    hy[o] = pk_(fmaxf(a0, 0.0f), fmaxf(a1, 0.0f));
  }
  float acc = p[156];
#pragma unroll
  for (int i = 0; i < 4; ++i) acc = fdot2_(w2[i], hy[i], acc);
  return acc;
}

// -------- setup: proj matrices (1 lane) + f16 weight packing (lane-parallel)
__global__ void k_setup(const float* __restrict__ refP, const float* __restrict__ srcP,
                        const float* __restrict__ pw0, const float* __restrict__ pbn0,
                        const float* __restrict__ pw1, const float* __restrict__ pbn1,
                        const float* __restrict__ pw2, const float* __restrict__ pb2,
                        const float* __restrict__ sw0, const float* __restrict__ sbn0,
                        const float* __restrict__ sw1, const float* __restrict__ sbn1,
                        const float* __restrict__ sw2, const float* __restrict__ sb2,
                        float* __restrict__ ws) {
  int tid = threadIdx.x;
  if (tid == 578) {
    float a[4][8];
    for (int i = 0; i < 4; ++i)
      for (int j = 0; j < 4; ++j) { a[i][j] = refP[i * 4 + j]; a[i][4 + j] = (i == j) ? 1.0f : 0.0f; }
    for (int c = 0; c < 4; ++c) {
      int piv = c; float best = fabsf(a[c][c]);
      for (int r = c + 1; r < 4; ++r) { float t = fabsf(a[r][c]); if (t > best) { best = t; piv = r; } }
      if (piv != c) for (int j = 0; j < 8; ++j) { float t = a[c][j]; a[c][j] = a[piv][j]; a[piv][j] = t; }
      float inv = 1.0f / a[c][c];
      for (int j = 0; j < 8; ++j) a[c][j] *= inv;
      for (int r = 0; r < 4; ++r) if (r != c) {
        float f = a[r][c];
        for (int j = 0; j < 8; ++j) a[r][j] -= f * a[c][j];
      }
    }
    for (int v = 0; v < NVIEW; ++v) {
      const float* S = srcP + v * 16;
      for (int i = 0; i < 3; ++i)
        for (int j = 0; j < 4; ++j) {
          float p = S[i*4+0]*a[0][4+j] + S[i*4+1]*a[1][4+j] + S[i*4+2]*a[2][4+j] + S[i*4+3]*a[3][4+j];
          if (j < 3) ws[v * 12 + i * 3 + j] = p;
          else       ws[v * 12 + 9 + i] = p;
        }
    }
    return;
  }
  if (tid >= 578) return;
  int k = tid / 289;
  int j = tid - k * 289;
  const float* W0 = k ? sw0 : pw0;  const float* B0 = k ? sbn0 : pbn0;
  const float* W1 = k ? sw1 : pw1;  const float* B1 = k ? sbn1 : pbn1;
  const float* W2 = k ? sw2 : pw2;  const float* B2 = k ? sb2 : pb2;
  float* p = ws + (k ? OFF_SN : OFF_PW);
  __half* w0h = (__half*)p;
  __half* w1h = (__half*)(p + 64);
  __half* w2h = (__half*)(p + 128);
  if (j < 128) {                       // layer0 weights: BN scale * 0.25 group-mean folded
    int o = j >> 3;
    float s = B0[o] / sqrtf(B0[48 + o] + 1e-5f);
    w0h[j] = __float2half_rn(W0[j] * s * 0.25f);
  } else if (j < 256) {                // layer1 weights
    int idx = j - 128; int o = idx >> 4;
    float s = B1[o] / sqrtf(B1[24 + o] + 1e-5f);
    w1h[idx] = __float2half_rn(W1[idx] * s);
  } else if (j < 264) {
    w2h[j - 256] = __float2half_rn(W2[j - 256]);
  } else if (j < 280) {                // layer0 bias (f32)
    int o = j - 264;
    float s = B0[o] / sqrtf(B0[48 + o] + 1e-5f);
    p[132 + o] = B0[16 + o] - B0[32 + o] * s;
  } else if (j < 288) {                // layer1 bias (f32)
    int o = j - 280;
    float s = B1[o] / sqrtf(B1[24 + o] + 1e-5f);
    p[148 + o] = B1[8 + o] - B1[16 + o] * s;
  } else {
    p[156] = B2[0];
  }
}

// -------- transpose+convert (V,C,H,W) f32 -> (plane,H,W,C) f16; plane 4 = ref
__global__ __launch_bounds__(256) void k_transpose(const float* __restrict__ src,
                                                   const float* __restrict__ ref,
                                                   __half* __restrict__ dst, int total) {
  int t = blockIdx.x * 256 + threadIdx.x;
  if (t >= total) return;
  int c8 = t & 3;                      // which 8-channel chunk
  int vp = t >> 2;                     // plane*HWPIX + pix
  int v = vp / HWPIX;
  int pix = vp - v * HWPIX;
  const float* s = (v < NVIEW) ? (src + ((size_t)(v * NCH + c8 * 8)) * HWPIX + pix)
                               : (ref + ((size_t)(c8 * 8)) * HWPIX + pix);
  union { h2 h[4]; float4 f; } u;
  u.h[0] = pk_(s[0],         s[HWPIX]);
  u.h[1] = pk_(s[2 * HWPIX], s[3 * HWPIX]);
  u.h[2] = pk_(s[4 * HWPIX], s[5 * HWPIX]);
  u.h[3] = pk_(s[6 * HWPIX], s[7 * HWPIX]);
  reinterpret_cast<float4*>(dst + (size_t)vp * NCH)[c8] = u.f;
}

__device__ __forceinline__ void tap_f16(const __half* __restrict__ p, float wtf,
                                        h2 wp[16], bool first) {
  _Float16 wh = (_Float16)wtf;
  h2 wt2 = h2{wh, wh};
  const float4* q = reinterpret_cast<const float4*>(p);
#pragma unroll
  for (int i = 0; i < 4; ++i) {
    union { float4 f; h2 h[4]; } u; u.f = q[i];
#pragma unroll
    for (int c = 0; c < 4; ++c) {
      if (first) wp[4 * i + c] = u.h[c] * wt2;
      else       wp[4 * i + c] += u.h[c] * wt2;
    }
  }
}

// -------- main fused kernel. MODE 1: f16 transposed features. MODE 0: direct f32 CHW.
template <int MODE>
__global__ __launch_bounds__(256) void k_main(
    const float* __restrict__ ref, const float* __restrict__ src,
    const __half* __restrict__ srcT,
    const float* __restrict__ depthS, const float* __restrict__ wsc,
    float* __restrict__ ybuf, float* __restrict__ outVW) {
  int t = blockIdx.x * 256 + threadIdx.x;
  int d = t & 7;
  int pix = t >> 3;
  int h = pix / WW;
  int w = pix - h * WW;
  float fx = (float)w, fy = (float)h;

  h2 rc[16];        // MODE 1: ref channels packed
  float rcf[(MODE == 0) ? NCH : 1];
  if (MODE == 1) {
    const float4* rp = reinterpret_cast<const float4*>(srcT + (size_t)NVIEW * SPLANE + (size_t)pix * NCH);
#pragma unroll
    for (int i = 0; i < 4; ++i) {
      union { float4 f; h2 h[4]; } u; u.f = rp[i];
      rc[4*i] = u.h[0]; rc[4*i+1] = u.h[1]; rc[4*i+2] = u.h[2]; rc[4*i+3] = u.h[3];
    }
  } else {
#pragma unroll
    for (int c = 0; c < NCH; ++c) rcf[c] = ref[c * HWPIX + pix];
  }
  float dep = depthS[d * HWPIX + pix];

  float ssum[NGRP];
#pragma unroll
  for (int g = 0; g < NGRP; ++g) ssum[g] = 0.0f;
  float wsum = 0.0f;

#pragma unroll 1
  for (int v = 0; v < NVIEW; ++v) {
    const float* pr = wsc + v * 12;
    float rx = fmaf(pr[0], fx, fmaf(pr[1], fy, pr[2]));
    float ry = fmaf(pr[3], fx, fmaf(pr[4], fy, pr[5]));
    float rz = fmaf(pr[6], fx, fmaf(pr[7], fy, pr[8]));
    float pz_ = fmaf(rz, dep, pr[11]);
    bool neg = (pz_ <= 0.001f);
    float px_ = neg ? (float)WW : fmaf(rx, dep, pr[9]);
    float py_ = neg ? (float)HH : fmaf(ry, dep, pr[10]);
    float rpz = neg ? 1.0f : __fdividef(1.0f, pz_);
    float ix = px_ * rpz;      // align_corners=True algebra: ix = px/pz
    float iy = py_ * rpz;
    float x0f = floorf(ix), y0f = floorf(iy);
    float wx1 = ix - x0f, wy1 = iy - y0f;
    float wx0 = 1.0f - wx1, wy0 = 1.0f - wy1;
    float x1f = x0f + 1.0f, y1f = y0f + 1.0f;
    float vx0 = (x0f >= 0.0f && x0f <= (float)(WW - 1)) ? 1.0f : 0.0f;
    float vx1 = (x1f >= 0.0f && x1f <= (float)(WW - 1)) ? 1.0f : 0.0f;
    float vy0 = (y0f >= 0.0f && y0f <= (float)(HH - 1)) ? 1.0f : 0.0f;
    float vy1 = (y1f >= 0.0f && y1f <= (float)(HH - 1)) ? 1.0f : 0.0f;
    int xa = (int)fminf(fmaxf(x0f, 0.0f), (float)(WW - 1));
    int xb = (int)fminf(fmaxf(x1f, 0.0f), (float)(WW - 1));
    int ya = (int)fminf(fmaxf(y0f, 0.0f), (float)(HH - 1));
    int yb = (int)fminf(fmaxf(y1f, 0.0f), (float)(HH - 1));
    float w00 = wx0 * wy0 * vx0 * vy0;   // zeros_pad=True
    float w01 = wx1 * wy0 * vx1 * vy0;
    float w10 = wx0 * wy1 * vx0 * vy1;
    float w11 = wx1 * wy1 * vx1 * vy1;

    float simf[NGRP];
    if (MODE == 1) {
      const __half* vbase = srcT + (size_t)v * SPLANE;
      h2 wp[16];
      tap_f16(vbase + (size_t)(ya * WW + xa) * NCH, w00, wp, true);
      tap_f16(vbase + (size_t)(ya * WW + xb) * NCH, w01, wp, false);
      tap_f16(vbase + (size_t)(yb * WW + xa) * NCH, w10, wp, false);
      tap_f16(vbase + (size_t)(yb * WW + xb) * NCH, w11, wp, false);
#pragma unroll
      for (int g = 0; g < NGRP; ++g)
        simf[g] = fdot2_(wp[2*g+1], rc[2*g+1], fdot2_(wp[2*g], rc[2*g], 0.0f));
    } else {
      const float* base = src + (size_t)v * NCH * HWPIX;
      const float* p00 = base + ya * WW + xa;
      const float* p01 = base + ya * WW + xb;
      const float* p10 = base + yb * WW + xa;
      const float* p11 = base + yb * WW + xb;
#pragma unroll
      for (int g = 0; g < NGRP; ++g) {
        float acc = 0.0f;
#pragma unroll
        for (int cc = 0; cc < 4; ++cc) {
          size_t o = (size_t)(g * 4 + cc) * HWPIX;
          float wv = w00 * p00[o] + w01 * p01[o] + w10 * p10[o] + w11 * p11[o];
          acc = fmaf(wv, rcf[g * 4 + cc], acc);
        }
        simf[g] = acc;
      }
    }

    h2 x[4];
#pragma unroll
    for (int i = 0; i < 4; ++i) x[i] = pk_(simf[2*i], simf[2*i+1]);
    float sc = mlp_h(wsc + OFF_PW, x);
    sc = fmaxf(sc, __shfl_xor(sc, 1, 8));   // sigmoid monotonic: max before sigmoid
    sc = fmaxf(sc, __shfl_xor(sc, 2, 8));
    sc = fmaxf(sc, __shfl_xor(sc, 4, 8));
    float vw = __fdividef(1.0f, 1.0f + __expf(-sc));
#pragma unroll
    for (int g = 0; g < NGRP; ++g) ssum[g] = fmaf(simf[g], vw, ssum[g]);
    wsum += vw;
    if (d == 0) outVW[v * HWPIX + pix] = vw;
  }

  float rw = __fdividef(1.0f, wsum);
  h2 xg[4];
#pragma unroll
  for (int i = 0; i < 4; ++i) xg[i] = pk_(ssum[2*i] * rw, ssum[2*i+1] * rw);
  float yv = mlp_h(wsc + OFF_SN, xg);
  ybuf[pix * NDEP + d] = yv;               // [pix][d] coalesced
}

// -------- score: 9-neighbor grid_sample of y + weight dot + softmax + depth
__global__ __launch_bounds__(256) void k_score(
    const float* __restrict__ grid, const float* __restrict__ weight,
    const float* __restrict__ depthS, const float* __restrict__ ybuf,
    float* __restrict__ out) {
  int t = blockIdx.x * 256 + threadIdx.x;
  int d = t & 7;
  int pix = t >> 3;
  int h = pix / WW;
  int w = pix - h * WW;
  float sv = 0.0f;
#pragma unroll 1
  for (int n = 0; n < NNEI; ++n) {
    int gi = ((n * HH + h) * WW + w) * 2;
    float gx = grid[gi], gy = grid[gi + 1];
    float ix = ((gx + 1.0f) * (float)WW - 1.0f) * 0.5f;  // align_corners=False
    float iy = ((gy + 1.0f) * (float)HH - 1.0f) * 0.5f;
    float x0f = floorf(ix), y0f = floorf(iy);
    float wx1 = ix - x0f, wy1 = iy - y0f;
    float wx0 = 1.0f - wx1, wy0 = 1.0f - wy1;
    int xa = (int)fminf(fmaxf(x0f, 0.0f), (float)(WW - 1));
    int xb = (int)fminf(fmaxf(x0f + 1.0f, 0.0f), (float)(WW - 1));
    int ya = (int)fminf(fmaxf(y0f, 0.0f), (float)(HH - 1));
    int yb2 = (int)fminf(fmaxf(y0f + 1.0f, 0.0f), (float)(HH - 1));
    float v00 = ybuf[(ya * WW + xa) * NDEP + d], v01 = ybuf[(ya * WW + xb) * NDEP + d];
    float v10 = ybuf[(yb2 * WW + xa) * NDEP + d], v11 = ybuf[(yb2 * WW + xb) * NDEP + d];
    float s = wy0 * fmaf(wx0, v00, wx1 * v01) + wy1 * fmaf(wx0, v10, wx1 * v11);
    float wn = weight[((d * NNEI + n) * HH + h) * WW + w];
    sv = fmaf(s, wn, sv);
  }
  float m = sv;
  m = fmaxf(m, __shfl_xor(m, 1, 8));
  m = fmaxf(m, __shfl_xor(m, 2, 8));
  m = fmaxf(m, __shfl_xor(m, 4, 8));
  float e = __expf(sv - m);
  float s8 = e;
  s8 += __shfl_xor(s8, 1, 8);
  s8 += __shfl_xor(s8, 2, 8);
  s8 += __shfl_xor(s8, 4, 8);
  float sc = __fdividef(e, s8);
  out[HWPIX + d * HWPIX + pix] = sc;           // score
  float dp = depthS[d * HWPIX + pix] * sc;
  dp += __shfl_xor(dp, 1, 8);
  dp += __shfl_xor(dp, 2, 8);
  dp += __shfl_xor(dp, 4, 8);
  if (d == 0) out[pix] = dp;                   // depth
}

extern "C" void kernel_launch(void* const* d_in, const int* in_sizes, int n_in,
                              void* d_out, int out_size, void* d_ws, size_t ws_size,
                              hipStream_t stream) {
  const float* ref    = (const float*)d_in[0];
  const float* src    = (const float*)d_in[1];
  const float* refP   = (const float*)d_in[2];
  const float* srcP   = (const float*)d_in[3];
  const float* depthS = (const float*)d_in[4];
  const float* grid   = (const float*)d_in[5];
  const float* weight = (const float*)d_in[6];
  float* out = (float*)d_out;
  float* ws  = (float*)d_ws;
  __half* srcT = (__half*)(ws + OFF_SRCT);

  size_t need = (size_t)OFF_SRCT * 4 + (size_t)5 * SPLANE * 2;
  int mode = (ws_size >= need) ? 1 : 0;

  k_setup<<<1, 640, 0, stream>>>(refP, srcP,
                                 (const float*)d_in[7], (const float*)d_in[8],
                                 (const float*)d_in[9], (const float*)d_in[10],
                                 (const float*)d_in[11], (const float*)d_in[12],
                                 (const float*)d_in[13], (const float*)d_in[14],
                                 (const float*)d_in[15], (const float*)d_in[16],
                                 (const float*)d_in[17], (const float*)d_in[18], ws);
  if (mode == 1) {
    int total = 5 * HWPIX * 4;
    k_transpose<<<(total + 255) / 256, 256, 0, stream>>>(src, ref, srcT, total);
    k_main<1><<<(HWPIX * 8) / 256, 256, 0, stream>>>(ref, src, srcT, depthS, ws,
                                                     ws + OFF_Y, out + 9 * HWPIX);
  } else {
    k_main<0><<<(HWPIX * 8) / 256, 256, 0, stream>>>(ref, src, srcT, depthS, ws,
                                                     ws + OFF_Y, out + 9 * HWPIX);
  }
  k_score<<<(HWPIX * 8) / 256, 256, 0, stream>>>(grid, weight, depthS, ws + OFF_Y, out);
}